// Round 3
// baseline (7588.264 us; speedup 1.0000x reference)
//
#include <hip/hip_runtime.h>
#include <hip/hip_bf16.h>

#define BATCH 64
#define IN_SIZE 4096
#define IN_DIM 128
#define HEADS 2
#define OUT_SIZE 128
#define NPAIR (BATCH*HEADS)
#define INV_EPS 10.0f
#define MAX_ITER 50
#define A_MARG (1.0f/32.0f)

typedef unsigned int u32;
typedef __attribute__((ext_vector_type(8))) short bf16x8;
typedef __attribute__((ext_vector_type(4))) float f32x4;

__device__ __forceinline__ float bflo(u32 kk){ return __uint_as_float(kk<<16); }
__device__ __forceinline__ float bfhi(u32 kk){ return __uint_as_float(kk & 0xffff0000u); }
__device__ __forceinline__ unsigned short f2bf(float f){
    __hip_bfloat16 h = __float2bfloat16(f);
    return *(unsigned short*)&h;
}

template<int CTRL>
__device__ __forceinline__ float dpp_add(float x) {
    int yi = __builtin_amdgcn_update_dpp(0, __float_as_int(x), CTRL, 0xf, 0xf, false);
    return x + __int_as_float(yi);
}

// ---------------------------------------------------------------------------
// Kernel 1: kgen (MFMA). Kb[p][i][o] = bf16(exp(10 * x[n,i,:].w[m,o,:]))
// block 256 (4 waves); tile 128 i x 128 o; pair = blockIdx.y
// LDS: x-tile and w-tile as bf16, byte ^= (row&7)<<4 swizzle.
// ---------------------------------------------------------------------------
__global__ __launch_bounds__(256) void kgen(const float* __restrict__ x,
                                            const float* __restrict__ w,
                                            __hip_bfloat16* __restrict__ Kb)
{
    const int pair = blockIdx.y;
    const int n = pair >> 1, m = pair & 1;
    const int r0 = blockIdx.x * 128;
    const int tid = threadIdx.x;
    const int wv  = tid >> 6;
    const int l   = tid & 63;

    __shared__ char xs[128*256];   // [i][d] bf16 swizzled
    __shared__ char ws[128*256];   // [o][d] bf16 swizzled

    {   // stage x rows -> bf16 swizzled
        const float* xb = x + ((size_t)n*IN_SIZE + r0)*IN_DIM;
        for (int t = tid; t < 4096; t += 256) {
            int row = t >> 5, c4 = t & 31;
            float4 v4 = *(const float4*)&xb[(size_t)row*IN_DIM + c4*4];
            u32 p0 = (u32)f2bf(v4.x) | ((u32)f2bf(v4.y) << 16);
            u32 p1 = (u32)f2bf(v4.z) | ((u32)f2bf(v4.w) << 16);
            int byte = (row*256 + c4*8) ^ ((row & 7) << 4);
            *(u32*)(xs + byte)     = p0;
            *(u32*)(xs + byte + 4) = p1;
        }
    }
    {   // stage w[m] rows -> bf16 swizzled
        const float* wb = w + (size_t)m*OUT_SIZE*IN_DIM;
        for (int t = tid; t < 4096; t += 256) {
            int row = t >> 5, c4 = t & 31;
            float4 v4 = *(const float4*)&wb[(size_t)row*IN_DIM + c4*4];
            u32 p0 = (u32)f2bf(v4.x) | ((u32)f2bf(v4.y) << 16);
            u32 p1 = (u32)f2bf(v4.z) | ((u32)f2bf(v4.w) << 16);
            int byte = (row*256 + c4*8) ^ ((row & 7) << 4);
            *(u32*)(ws + byte)     = p0;
            *(u32*)(ws + byte + 4) = p1;
        }
    }
    __syncthreads();

    f32x4 acc[2][8];
    #pragma unroll
    for (int ai=0;ai<2;++ai)
        #pragma unroll
        for (int bj=0;bj<8;++bj) acc[ai][bj] = (f32x4){0.f,0.f,0.f,0.f};

    const int lr = l & 15;          // fragment row lane part
    const int lk = (l >> 4) * 16;   // k byte offset lane part

    #pragma unroll
    for (int kk = 0; kk < 4; ++kk) {
        bf16x8 a[2];
        #pragma unroll
        for (int ai=0;ai<2;++ai) {
            int row = wv*32 + ai*16 + lr;
            int byte = (row*256 + kk*64 + lk) ^ ((row & 7) << 4);
            a[ai] = *(const bf16x8*)(xs + byte);
        }
        #pragma unroll
        for (int bj=0;bj<8;++bj) {
            int row = bj*16 + lr;
            int byte = (row*256 + kk*64 + lk) ^ ((row & 7) << 4);
            bf16x8 b = *(const bf16x8*)(ws + byte);
            acc[0][bj] = __builtin_amdgcn_mfma_f32_16x16x32_bf16(a[0], b, acc[0][bj], 0, 0, 0);
            acc[1][bj] = __builtin_amdgcn_mfma_f32_16x16x32_bf16(a[1], b, acc[1][bj], 0, 0, 0);
        }
    }

    // epilogue: exp -> bf16 -> store K[i][o]
    __hip_bfloat16* out = Kb + (size_t)pair*IN_SIZE*OUT_SIZE + (size_t)r0*OUT_SIZE;
    #pragma unroll
    for (int ai=0;ai<2;++ai) {
        #pragma unroll
        for (int bj=0;bj<8;++bj) {
            #pragma unroll
            for (int j=0;j<4;++j) {
                int i = wv*32 + ai*16 + (l>>4)*4 + j;
                int o = bj*16 + lr;
                float e = __expf(INV_EPS * acc[ai][bj][j]);
                out[(size_t)i*OUT_SIZE + o] = __float2bfloat16(e);
            }
        }
    }
}

// ---------------------------------------------------------------------------
// Kernel 2: sinkhorn, split 2 blocks/pair (256 blocks x 1024 thr).
// Each block: 2048 rows; 16 waves x 128 rows; 16-lane group per row,
// DPP row reduce. Per-iteration 128-float colsum exchange via psG + flags.
// ---------------------------------------------------------------------------
__global__ __launch_bounds__(1024) void sinkhorn(const __hip_bfloat16* __restrict__ Kb,
                                                 float* __restrict__ uo,
                                                 float* __restrict__ vo,
                                                 float* __restrict__ psG,
                                                 unsigned int* __restrict__ flags)
{
    const int bid  = blockIdx.x;
    const int pair = bid >> 1, half = bid & 1;
    const int tid  = threadIdx.x;
    const int wave = tid >> 6;      // 16 waves, 128 rows each
    const int lane = tid & 63;
    const int grp  = lane >> 4;     // row within 4-row step
    const int s    = lane & 15;     // column slice 8s..8s+7

    __shared__ float red[16][128];
    __shared__ float vnew[128];

    const int4* gp = (const int4*)(Kb)
                   + ((size_t)pair*4096 + half*2048 + wave*128)*16
                   + grp*16 + s;

    unsigned int* myflag = flags + bid;
    unsigned int* otflag = flags + (bid ^ 1);
    float* myps = psG + (size_t)bid*2*128;
    float* otps = psG + (size_t)(bid^1)*2*128;

    float v[8];
    #pragma unroll
    for (int j=0;j<8;++j) v[j] = 1.f;

    for (int it = 0; it < MAX_ITER; ++it) {
        const bool last = (it == MAX_ITER-1);
        float acc[8];
        #pragma unroll
        for (int j=0;j<8;++j) acc[j] = 0.f;

        int4 c0 = gp[0], c1 = gp[64], c2 = gp[128], c3 = gp[192];
        for (int g = 0; g < 32; ++g) {
            int gn = g + 4; if (gn > 31) gn = 31;
            int4 nx = gp[(size_t)gn*64];
            float k[8];
            k[0]=bflo(c0.x); k[1]=bfhi(c0.x);
            k[2]=bflo(c0.y); k[3]=bfhi(c0.y);
            k[4]=bflo(c0.z); k[5]=bfhi(c0.z);
            k[6]=bflo(c0.w); k[7]=bfhi(c0.w);
            float p = k[0]*v[0];
            #pragma unroll
            for (int j=1;j<8;++j) p = fmaf(k[j], v[j], p);
            p = dpp_add<0xB1>(p);
            p = dpp_add<0x4E>(p);
            p = dpp_add<0x141>(p);
            p = dpp_add<0x140>(p);
            float ui = A_MARG * __builtin_amdgcn_rcpf(p);
            #pragma unroll
            for (int j=0;j<8;++j) acc[j] = fmaf(ui, k[j], acc[j]);
            if (last && s == 0)
                uo[(size_t)pair*IN_SIZE + half*2048 + wave*128 + g*4 + grp] = ui;
            c0 = c1; c1 = c2; c2 = c3; c3 = nx;
        }
        #pragma unroll
        for (int j=0;j<8;++j) {
            acc[j] += __shfl_xor(acc[j], 16, 64);
            acc[j] += __shfl_xor(acc[j], 32, 64);
        }
        if (lane < 16) {
            *(float4*)&red[wave][8*s]   = make_float4(acc[0],acc[1],acc[2],acc[3]);
            *(float4*)&red[wave][8*s+4] = make_float4(acc[4],acc[5],acc[6],acc[7]);
        }
        __syncthreads();
        float own = 0.f;
        if (tid < 128) {
            #pragma unroll
            for (int w_ = 0; w_ < 16; ++w_) own += red[w_][tid];
            __hip_atomic_store(&myps[(it&1)*128 + tid], own,
                               __ATOMIC_RELAXED, __HIP_MEMORY_SCOPE_AGENT);
        }
        __threadfence();
        __syncthreads();
        if (tid == 0) {
            __hip_atomic_store(myflag, (unsigned int)(it+1),
                               __ATOMIC_RELEASE, __HIP_MEMORY_SCOPE_AGENT);
            while (__hip_atomic_load(otflag, __ATOMIC_ACQUIRE,
                                     __HIP_MEMORY_SCOPE_AGENT) < (unsigned int)(it+1)) {
                __builtin_amdgcn_s_sleep(2);
            }
        }
        __syncthreads();
        if (tid < 128) {
            float other = __hip_atomic_load(&otps[(it&1)*128 + tid],
                                            __ATOMIC_RELAXED, __HIP_MEMORY_SCOPE_AGENT);
            float vv = __builtin_amdgcn_rcpf(own + other);
            vnew[tid] = vv;
            if (last && half == 0) vo[(size_t)pair*OUT_SIZE + tid] = vv;
        }
        __syncthreads();
        float4 va = *(const float4*)&vnew[8*s];
        float4 vb = *(const float4*)&vnew[8*s+4];
        v[0]=va.x; v[1]=va.y; v[2]=va.z; v[3]=va.w;
        v[4]=vb.x; v[5]=vb.y; v[6]=vb.z; v[7]=vb.w;
        __syncthreads();
    }
}

// ---------------------------------------------------------------------------
// Kernel 3: outgemm (MFMA). out[n][o][m][d] = v_o * sum_i (u_i K[i,o]) x[i,d]
// grid (2 d-halves, NPAIR); block 256 (4 waves). i chunks of 64.
// Per chunk: phase-a natural-layout stage, phase-b swizzled transposed
// bf16 tiles At[o][i] (u-folded), Bt[d][i]; then 16 mfma.
// ---------------------------------------------------------------------------
__global__ __launch_bounds__(256) void outgemm(const __hip_bfloat16* __restrict__ Kb,
                                               const float* __restrict__ uo,
                                               const float* __restrict__ vo,
                                               const float* __restrict__ x,
                                               float* __restrict__ out)
{
    const int dh = blockIdx.x;
    const int pair = blockIdx.y;
    const int n = pair >> 1, m = pair & 1;
    const int tid = threadIdx.x;
    const int wv  = tid >> 6;
    const int l   = tid & 63;

    __shared__ u32  ka[64][66];    // K chunk natural: [i][o-pair]
    __shared__ float ua[64];
    __shared__ float xa[64][68];   // x chunk natural: [i][d_local]
    __shared__ char At[128*128];   // [o][i] bf16 swizzled (128 rows x 128B)
    __shared__ char Bt[64*128];    // [d][i] bf16 swizzled ( 64 rows x 128B)

    f32x4 acc[2][4];
    #pragma unroll
    for (int ai=0;ai<2;++ai)
        #pragma unroll
        for (int bj=0;bj<4;++bj) acc[ai][bj] = (f32x4){0.f,0.f,0.f,0.f};

    const int lr = l & 15;
    const int lk = (l >> 4) * 16;

    for (int chunk = 0; chunk < 64; ++chunk) {
        const int i0 = chunk * 64;
        {   // phase a: K natural
            const u32* ksrc = (const u32*)(Kb + ((size_t)pair*IN_SIZE + i0)*OUT_SIZE);
            for (int t = tid; t < 4096; t += 256) ka[t>>6][t&63] = ksrc[t];
            if (tid < 64) ua[tid] = uo[(size_t)pair*IN_SIZE + i0 + tid];
            const float* xsrc = x + ((size_t)n*IN_SIZE + i0)*IN_DIM + dh*64;
            for (int t = tid; t < 1024; t += 256) {
                int i = t >> 4, c4 = t & 15;
                *(float4*)&xa[i][c4*4] = *(const float4*)&xsrc[(size_t)i*IN_DIM + c4*4];
            }
        }
        __syncthreads();
        {   // phase b: At (u-folded transpose of K)
            int o = tid >> 1, seg = tid & 1;
            u32 pk[8];
            #pragma unroll
            for (int q=0;q<8;++q) {
                int k0 = seg*32 + q*4;
                u32 r = 0;
                #pragma unroll
                for (int e=0;e<4;++e) {
                    int i = k0 + e;
                    u32 kk = ka[i][o>>1];
                    float f = (o&1) ? bfhi(kk) : bflo(kk);
                    f *= ua[i];
                    if (e & 1) { /* placeholder */ }
                    ((unsigned short*)&r)[e & 1] = f2bf(f);
                    if ((e & 1) == 1) { pk[q/1] = r; }
                    if (e == 1) pk[q] = r;
                }
                // rebuild properly (2 bf16 per u32, 4 elems -> 2 u32)
            }
            // The above is awkward; do it straightforwardly:
            unsigned short us[32];
            #pragma unroll
            for (int k=0;k<32;++k) {
                int i = seg*32 + k;
                u32 kk = ka[i][o>>1];
                float f = (o&1) ? bfhi(kk) : bflo(kk);
                us[k] = f2bf(f * ua[i]);
            }
            #pragma unroll
            for (int q=0;q<4;++q) {
                int4 wbuf;
                u32* wp = (u32*)&wbuf;
                #pragma unroll
                for (int e=0;e<4;++e)
                    wp[e] = (u32)us[q*8 + 2*e] | ((u32)us[q*8 + 2*e + 1] << 16);
                int byte = (o*128 + seg*64 + q*16) ^ ((o & 7) << 4);
                *(int4*)(At + byte) = wbuf;
            }
        }
        {   // phase b: Bt (transpose of x)
            int d = tid >> 2, s2 = tid & 3;
            unsigned short us[16];
            #pragma unroll
            for (int k=0;k<16;++k) us[k] = f2bf(xa[s2*16 + k][d]);
            #pragma unroll
            for (int q=0;q<2;++q) {
                int4 wbuf;
                u32* wp = (u32*)&wbuf;
                #pragma unroll
                for (int e=0;e<4;++e)
                    wp[e] = (u32)us[q*8 + 2*e] | ((u32)us[q*8 + 2*e + 1] << 16);
                int byte = (d*128 + s2*32 + q*16) ^ ((d & 7) << 4);
                *(int4*)(Bt + byte) = wbuf;
            }
        }
        __syncthreads();
        #pragma unroll
        for (int kk = 0; kk < 2; ++kk) {
            bf16x8 a[2];
            #pragma unroll
            for (int ai=0;ai<2;++ai) {
                int row = wv*32 + ai*16 + lr;
                int byte = (row*128 + kk*64 + lk) ^ ((row & 7) << 4);
                a[ai] = *(const bf16x8*)(At + byte);
            }
            #pragma unroll
            for (int bj=0;bj<4;++bj) {
                int row = bj*16 + lr;
                int byte = (row*128 + kk*64 + lk) ^ ((row & 7) << 4);
                bf16x8 b = *(const bf16x8*)(Bt + byte);
                acc[0][bj] = __builtin_amdgcn_mfma_f32_16x16x32_bf16(a[0], b, acc[0][bj], 0, 0, 0);
                acc[1][bj] = __builtin_amdgcn_mfma_f32_16x16x32_bf16(a[1], b, acc[1][bj], 0, 0, 0);
            }
        }
        __syncthreads();
    }

    #pragma unroll
    for (int ai=0;ai<2;++ai) {
        #pragma unroll
        for (int bj=0;bj<4;++bj) {
            #pragma unroll
            for (int j=0;j<4;++j) {
                int o = wv*32 + ai*16 + (l>>4)*4 + j;
                int d = dh*64 + bj*16 + lr;
                float vv = vo[(size_t)pair*OUT_SIZE + o];
                out[(((size_t)n*OUT_SIZE + o)*HEADS + m)*IN_DIM + d] = acc[ai][bj][j] * vv;
            }
        }
    }
}

// ---------------------------------------------------------------------------
extern "C" void kernel_launch(void* const* d_in, const int* in_sizes, int n_in,
                              void* d_out, int out_size, void* d_ws, size_t ws_size,
                              hipStream_t stream)
{
    const float* x = (const float*)d_in[0];
    const float* w = (const float*)d_in[1];
    float* out = (float*)d_out;

    char* ws = (char*)d_ws;
    __hip_bfloat16* Kb = (__hip_bfloat16*)ws;                         // 134,217,728
    float* uo   = (float*)(ws + 134217728);                           //   2,097,152
    float* vo   = (float*)(ws + 134217728 + 2097152);                 //      65,536
    float* psG  = (float*)(ws + 134217728 + 2097152 + 65536);         //     262,144
    unsigned int* flags = (unsigned int*)(ws + 134217728 + 2097152 + 65536 + 262144); // 1,024

    hipMemsetAsync(flags, 0, NPAIR*2*sizeof(unsigned int), stream);

    kgen    <<<dim3(IN_SIZE/128, NPAIR), 256,  0, stream>>>(x, w, Kb);
    sinkhorn<<<dim3(NPAIR*2),            1024, 0, stream>>>(Kb, uo, vo, psG, flags);
    outgemm <<<dim3(2, NPAIR),           256,  0, stream>>>(Kb, uo, vo, x, out);
}

// Round 4
// 1520.945 us; speedup vs baseline: 4.9892x; 4.9892x over previous
//
#include <hip/hip_runtime.h>
#include <hip/hip_bf16.h>

#define BATCH 64
#define IN_SIZE 4096
#define IN_DIM 128
#define HEADS 2
#define OUT_SIZE 128
#define NPAIR (BATCH*HEADS)
#define NBLK (NPAIR*2)
#define INV_EPS 10.0f
#define MAX_ITER 50
#define A_MARG (1.0f/32.0f)

typedef unsigned int u32;
typedef __attribute__((ext_vector_type(8))) short bf16x8;
typedef __attribute__((ext_vector_type(4))) float f32x4;

__device__ __forceinline__ float bflo(u32 kk){ return __uint_as_float(kk<<16); }
__device__ __forceinline__ float bfhi(u32 kk){ return __uint_as_float(kk & 0xffff0000u); }
__device__ __forceinline__ unsigned short f2bf(float f){
    __hip_bfloat16 h = __float2bfloat16(f);
    return *(unsigned short*)&h;
}

template<int CTRL>
__device__ __forceinline__ float dpp_add(float x) {
    int yi = __builtin_amdgcn_update_dpp(0, __float_as_int(x), CTRL, 0xf, 0xf, false);
    return x + __int_as_float(yi);
}

// ---------------------------------------------------------------------------
// Kernel 1: kgen (MFMA). Kb[p][i][o] = bf16(exp(10 * x[n,i,:].w[m,o,:]))
// (unchanged from round 3 — 128x128 tile, swizzled bf16 LDS, 16x16x32 MFMA)
// ---------------------------------------------------------------------------
__global__ __launch_bounds__(256) void kgen(const float* __restrict__ x,
                                            const float* __restrict__ w,
                                            __hip_bfloat16* __restrict__ Kb)
{
    const int pair = blockIdx.y;
    const int n = pair >> 1, m = pair & 1;
    const int r0 = blockIdx.x * 128;
    const int tid = threadIdx.x;
    const int wv  = tid >> 6;
    const int l   = tid & 63;

    __shared__ char xs[128*256];   // [i][d] bf16 swizzled
    __shared__ char ws[128*256];   // [o][d] bf16 swizzled

    {
        const float* xb = x + ((size_t)n*IN_SIZE + r0)*IN_DIM;
        for (int t = tid; t < 4096; t += 256) {
            int row = t >> 5, c4 = t & 31;
            float4 v4 = *(const float4*)&xb[(size_t)row*IN_DIM + c4*4];
            u32 p0 = (u32)f2bf(v4.x) | ((u32)f2bf(v4.y) << 16);
            u32 p1 = (u32)f2bf(v4.z) | ((u32)f2bf(v4.w) << 16);
            int byte = (row*256 + c4*8) ^ ((row & 7) << 4);
            *(u32*)(xs + byte)     = p0;
            *(u32*)(xs + byte + 4) = p1;
        }
    }
    {
        const float* wb = w + (size_t)m*OUT_SIZE*IN_DIM;
        for (int t = tid; t < 4096; t += 256) {
            int row = t >> 5, c4 = t & 31;
            float4 v4 = *(const float4*)&wb[(size_t)row*IN_DIM + c4*4];
            u32 p0 = (u32)f2bf(v4.x) | ((u32)f2bf(v4.y) << 16);
            u32 p1 = (u32)f2bf(v4.z) | ((u32)f2bf(v4.w) << 16);
            int byte = (row*256 + c4*8) ^ ((row & 7) << 4);
            *(u32*)(ws + byte)     = p0;
            *(u32*)(ws + byte + 4) = p1;
        }
    }
    __syncthreads();

    f32x4 acc[2][8];
    #pragma unroll
    for (int ai=0;ai<2;++ai)
        #pragma unroll
        for (int bj=0;bj<8;++bj) acc[ai][bj] = (f32x4){0.f,0.f,0.f,0.f};

    const int lr = l & 15;
    const int lk = (l >> 4) * 16;

    #pragma unroll
    for (int kk = 0; kk < 4; ++kk) {
        bf16x8 a[2];
        #pragma unroll
        for (int ai=0;ai<2;++ai) {
            int row = wv*32 + ai*16 + lr;
            int byte = (row*256 + kk*64 + lk) ^ ((row & 7) << 4);
            a[ai] = *(const bf16x8*)(xs + byte);
        }
        #pragma unroll
        for (int bj=0;bj<8;++bj) {
            int row = bj*16 + lr;
            int byte = (row*256 + kk*64 + lk) ^ ((row & 7) << 4);
            bf16x8 b = *(const bf16x8*)(ws + byte);
            acc[0][bj] = __builtin_amdgcn_mfma_f32_16x16x32_bf16(a[0], b, acc[0][bj], 0, 0, 0);
            acc[1][bj] = __builtin_amdgcn_mfma_f32_16x16x32_bf16(a[1], b, acc[1][bj], 0, 0, 0);
        }
    }

    __hip_bfloat16* out = Kb + (size_t)pair*IN_SIZE*OUT_SIZE + (size_t)r0*OUT_SIZE;
    #pragma unroll
    for (int ai=0;ai<2;++ai) {
        #pragma unroll
        for (int bj=0;bj<8;++bj) {
            #pragma unroll
            for (int j=0;j<4;++j) {
                int i = wv*32 + ai*16 + (l>>4)*4 + j;
                int o = bj*16 + lr;
                float e = __expf(INV_EPS * acc[ai][bj][j]);
                out[(size_t)i*OUT_SIZE + o] = __float2bfloat16(e);
            }
        }
    }
}

// ---------------------------------------------------------------------------
// Kernel 2: sinkhorn, 2 blocks/pair (256 blocks x 1024 thr), 2048 rows each.
// Per-iteration colsum exchange: fence-free message passing. Each (it,blk)
// has a private 512B slot; value passed THROUGH relaxed agent atomics with
// sign-bit sentinel (slots pre-zeroed; stored as -x so sign bit flags ready).
// No release/acquire -> no L2 invalidate/writeback, no shared-line ping-pong.
// ---------------------------------------------------------------------------
__global__ __launch_bounds__(1024) void sinkhorn(const __hip_bfloat16* __restrict__ Kb,
                                                 float* __restrict__ uo,
                                                 float* __restrict__ vo,
                                                 int* __restrict__ slots)
{
    const int bid  = blockIdx.x;
    const int pair = bid >> 1, half = bid & 1;
    const int tid  = threadIdx.x;
    const int wave = tid >> 6;      // 16 waves, 128 rows each
    const int lane = tid & 63;
    const int grp  = lane >> 4;     // row within 4-row step
    const int s    = lane & 15;     // column slice 8s..8s+7

    __shared__ float red[16][128];
    __shared__ float vnew[128];

    const int4* gp = (const int4*)(Kb)
                   + ((size_t)pair*4096 + half*2048 + wave*128)*16
                   + grp*16 + s;

    float v[8];
    #pragma unroll
    for (int j=0;j<8;++j) v[j] = 1.f;

    for (int it = 0; it < MAX_ITER; ++it) {
        const bool last = (it == MAX_ITER-1);
        float acc[8];
        #pragma unroll
        for (int j=0;j<8;++j) acc[j] = 0.f;

        int4 c0 = gp[0], c1 = gp[64], c2 = gp[128], c3 = gp[192];
        for (int g = 0; g < 32; ++g) {
            int gn = g + 4; if (gn > 31) gn = 31;
            int4 nx = gp[(size_t)gn*64];
            float k[8];
            k[0]=bflo(c0.x); k[1]=bfhi(c0.x);
            k[2]=bflo(c0.y); k[3]=bfhi(c0.y);
            k[4]=bflo(c0.z); k[5]=bfhi(c0.z);
            k[6]=bflo(c0.w); k[7]=bfhi(c0.w);
            float p = k[0]*v[0];
            #pragma unroll
            for (int j=1;j<8;++j) p = fmaf(k[j], v[j], p);
            p = dpp_add<0xB1>(p);
            p = dpp_add<0x4E>(p);
            p = dpp_add<0x141>(p);
            p = dpp_add<0x140>(p);
            float ui = A_MARG * __builtin_amdgcn_rcpf(p);
            #pragma unroll
            for (int j=0;j<8;++j) acc[j] = fmaf(ui, k[j], acc[j]);
            if (last && s == 0)
                uo[(size_t)pair*IN_SIZE + half*2048 + wave*128 + g*4 + grp] = ui;
            c0 = c1; c1 = c2; c2 = c3; c3 = nx;
        }
        #pragma unroll
        for (int j=0;j<8;++j) {
            acc[j] += __shfl_xor(acc[j], 16, 64);
            acc[j] += __shfl_xor(acc[j], 32, 64);
        }
        if (lane < 16) {
            *(float4*)&red[wave][8*s]   = make_float4(acc[0],acc[1],acc[2],acc[3]);
            *(float4*)&red[wave][8*s+4] = make_float4(acc[4],acc[5],acc[6],acc[7]);
        }
        __syncthreads();
        if (tid < 128) {
            float own = 0.f;
            #pragma unroll
            for (int w_ = 0; w_ < 16; ++w_) own += red[w_][tid];
            // publish -own (sign bit == ready sentinel; own > 0 always)
            int* myslot = slots + ((size_t)it*NBLK + bid)*128;
            int* otslot = slots + ((size_t)it*NBLK + (bid^1))*128;
            __hip_atomic_store(&myslot[tid], __float_as_int(-own),
                               __ATOMIC_RELAXED, __HIP_MEMORY_SCOPE_AGENT);
            int wrd;
            do {
                wrd = __hip_atomic_load(&otslot[tid], __ATOMIC_RELAXED,
                                        __HIP_MEMORY_SCOPE_AGENT);
            } while (wrd >= 0);   // waits for sign bit (slot pre-zeroed)
            float other = -__int_as_float(wrd);
            float vv = __builtin_amdgcn_rcpf(own + other);
            vnew[tid] = vv;
            if (last && half == 0) vo[(size_t)pair*OUT_SIZE + tid] = vv;
        }
        __syncthreads();
        float4 va = *(const float4*)&vnew[8*s];
        float4 vb = *(const float4*)&vnew[8*s+4];
        v[0]=va.x; v[1]=va.y; v[2]=va.z; v[3]=va.w;
        v[4]=vb.x; v[5]=vb.y; v[6]=vb.z; v[7]=vb.w;
    }
}

// ---------------------------------------------------------------------------
// Kernel 3: outgemm (MFMA). out[n][o][m][d] = v_o * sum_i (u_i K[i,o]) x[i,d]
// (round-3 structure, dead code removed)
// ---------------------------------------------------------------------------
__global__ __launch_bounds__(256) void outgemm(const __hip_bfloat16* __restrict__ Kb,
                                               const float* __restrict__ uo,
                                               const float* __restrict__ vo,
                                               const float* __restrict__ x,
                                               float* __restrict__ out)
{
    const int dh = blockIdx.x;
    const int pair = blockIdx.y;
    const int n = pair >> 1, m = pair & 1;
    const int tid = threadIdx.x;
    const int wv  = tid >> 6;
    const int l   = tid & 63;

    __shared__ u32  ka[64][66];    // K chunk natural: [i][o-pair]
    __shared__ float ua[64];
    __shared__ float xa[64][68];   // x chunk natural: [i][d_local]
    __shared__ char At[128*128];   // [o][i] bf16 swizzled
    __shared__ char Bt[64*128];    // [d][i] bf16 swizzled

    f32x4 acc[2][4];
    #pragma unroll
    for (int ai=0;ai<2;++ai)
        #pragma unroll
        for (int bj=0;bj<4;++bj) acc[ai][bj] = (f32x4){0.f,0.f,0.f,0.f};

    const int lr = l & 15;
    const int lk = (l >> 4) * 16;

    for (int chunk = 0; chunk < 64; ++chunk) {
        const int i0 = chunk * 64;
        {
            const u32* ksrc = (const u32*)(Kb + ((size_t)pair*IN_SIZE + i0)*OUT_SIZE);
            for (int t = tid; t < 4096; t += 256) ka[t>>6][t&63] = ksrc[t];
            if (tid < 64) ua[tid] = uo[(size_t)pair*IN_SIZE + i0 + tid];
            const float* xsrc = x + ((size_t)n*IN_SIZE + i0)*IN_DIM + dh*64;
            for (int t = tid; t < 1024; t += 256) {
                int i = t >> 4, c4 = t & 15;
                *(float4*)&xa[i][c4*4] = *(const float4*)&xsrc[(size_t)i*IN_DIM + c4*4];
            }
        }
        __syncthreads();
        {   // At: u-folded transpose of K -> [o][i] bf16 swizzled
            int o = tid >> 1, seg = tid & 1;
            unsigned short us[32];
            #pragma unroll
            for (int k=0;k<32;++k) {
                int i = seg*32 + k;
                u32 kk = ka[i][o>>1];
                float f = (o&1) ? bfhi(kk) : bflo(kk);
                us[k] = f2bf(f * ua[i]);
            }
            #pragma unroll
            for (int q=0;q<4;++q) {
                int4 wbuf;
                u32* wp = (u32*)&wbuf;
                #pragma unroll
                for (int e=0;e<4;++e)
                    wp[e] = (u32)us[q*8 + 2*e] | ((u32)us[q*8 + 2*e + 1] << 16);
                int byte = (o*128 + seg*64 + q*16) ^ ((o & 7) << 4);
                *(int4*)(At + byte) = wbuf;
            }
        }
        {   // Bt: transpose of x -> [d][i] bf16 swizzled
            int d = tid >> 2, s2 = tid & 3;
            unsigned short us[16];
            #pragma unroll
            for (int k=0;k<16;++k) us[k] = f2bf(xa[s2*16 + k][d]);
            #pragma unroll
            for (int q=0;q<2;++q) {
                int4 wbuf;
                u32* wp = (u32*)&wbuf;
                #pragma unroll
                for (int e=0;e<4;++e)
                    wp[e] = (u32)us[q*8 + 2*e] | ((u32)us[q*8 + 2*e + 1] << 16);
                int byte = (d*128 + s2*32 + q*16) ^ ((d & 7) << 4);
                *(int4*)(Bt + byte) = wbuf;
            }
        }
        __syncthreads();
        #pragma unroll
        for (int kk = 0; kk < 2; ++kk) {
            bf16x8 a[2];
            #pragma unroll
            for (int ai=0;ai<2;++ai) {
                int row = wv*32 + ai*16 + lr;
                int byte = (row*128 + kk*64 + lk) ^ ((row & 7) << 4);
                a[ai] = *(const bf16x8*)(At + byte);
            }
            #pragma unroll
            for (int bj=0;bj<4;++bj) {
                int row = bj*16 + lr;
                int byte = (row*128 + kk*64 + lk) ^ ((row & 7) << 4);
                bf16x8 b = *(const bf16x8*)(Bt + byte);
                acc[0][bj] = __builtin_amdgcn_mfma_f32_16x16x32_bf16(a[0], b, acc[0][bj], 0, 0, 0);
                acc[1][bj] = __builtin_amdgcn_mfma_f32_16x16x32_bf16(a[1], b, acc[1][bj], 0, 0, 0);
            }
        }
        __syncthreads();
    }

    #pragma unroll
    for (int ai=0;ai<2;++ai) {
        #pragma unroll
        for (int bj=0;bj<4;++bj) {
            #pragma unroll
            for (int j=0;j<4;++j) {
                int o = wv*32 + ai*16 + (l>>4)*4 + j;
                int d = dh*64 + bj*16 + lr;
                float vv = vo[(size_t)pair*OUT_SIZE + o];
                out[(((size_t)n*OUT_SIZE + o)*HEADS + m)*IN_DIM + d] = acc[ai][bj][j] * vv;
            }
        }
    }
}

// ---------------------------------------------------------------------------
extern "C" void kernel_launch(void* const* d_in, const int* in_sizes, int n_in,
                              void* d_out, int out_size, void* d_ws, size_t ws_size,
                              hipStream_t stream)
{
    const float* x = (const float*)d_in[0];
    const float* w = (const float*)d_in[1];
    float* out = (float*)d_out;

    char* ws = (char*)d_ws;
    __hip_bfloat16* Kb = (__hip_bfloat16*)ws;                 // 134,217,728 B
    float* uo  = (float*)(ws + 134217728);                    //   2,097,152 B
    float* vo  = (float*)(ws + 134217728 + 2097152);          //      65,536 B
    int* slots = (int*)(ws + 134217728 + 2097152 + 65536);    //   6,553,600 B (50*256*128*4)

    // slots MUST be zeroed (harness poisons ws with 0xAA = sign bit set,
    // which would false-trigger the sentinel)
    hipMemsetAsync(slots, 0, (size_t)MAX_ITER*NBLK*128*sizeof(int), stream);

    kgen    <<<dim3(IN_SIZE/128, NPAIR), 256,  0, stream>>>(x, w, Kb);
    sinkhorn<<<dim3(NBLK),               1024, 0, stream>>>(Kb, uo, vo, slots);
    outgemm <<<dim3(2, NPAIR),           256,  0, stream>>>(Kb, uo, vo, x, out);
}